// Round 4
// baseline (71.195 us; speedup 1.0000x reference)
//
#include <hip/hip_runtime.h>

// Depthwise xcorr: out[p][oy][ox] = sum_{ky,kx} x[p][oy+ky][ox+kx] * z[p][ky][kx]
// 32768 planes. x: 31x31, z: 7x7, out: 25x25, fp32.
//
// Round 4: LDS-free version. Round-3 counters showed latency-bound (occ 20%,
// VALU 34%, HBM 18%, 5.7M LDS bank conflicts): 50KB LDS capped occupancy and
// the staging phase serialized. Now each thread = one 5x5 output tile, reads
// its 11x11 patch straight from global via immediate-offset dword loads
// (L1/L2 absorb the 3.15x overlap), z plane held in 49 VGPRs. No LDS, no
// barrier, no divergence.

#define HX 31
#define WX 31
#define HO 25
#define WO 25
#define XPLANE (HX * WX)   // 961
#define ZPLANE 49
#define OPLANE (HO * WO)   // 625

__global__ __launch_bounds__(256) void dwxcorr_kernel(
    const float* __restrict__ z, const float* __restrict__ x,
    float* __restrict__ out, int ntiles) {
  const int gid = blockIdx.x * 256 + threadIdx.x;
  if (gid >= ntiles) return;

  // tile id -> (plane, ty, tx); consecutive lanes = consecutive tx (coalesced-ish)
  const int plane = gid / 25;           // magic-div (constant)
  const int t25 = gid - plane * 25;
  const int ty = t25 / 5;
  const int tx = t25 - ty * 5;

  // z plane -> 49 registers (25 lanes/plane share addresses -> coalesced)
  const float* zb = z + (size_t)plane * ZPLANE;
  float zr[ZPLANE];
#pragma unroll
  for (int j = 0; j < ZPLANE; ++j) zr[j] = zb[j];

  // base of this tile's 11x11 input patch; all 121 loads are base + imm
  const float* xb = x + (size_t)plane * XPLANE + (ty * 5) * WX + tx * 5;

  float acc[5][5];
#pragma unroll
  for (int r = 0; r < 5; ++r)
#pragma unroll
    for (int j = 0; j < 5; ++j) acc[r][j] = 0.0f;

  // Stream 11 patch rows; row iy feeds output rows orow = iy-ky, ky in [0,6]
#pragma unroll
  for (int iy = 0; iy < 11; ++iy) {
    float xr[11];
#pragma unroll
    for (int k = 0; k < 11; ++k) xr[k] = xb[iy * WX + k];
    const int ky_lo = (iy - 4 < 0) ? 0 : iy - 4;
    const int ky_hi = (iy < 6) ? iy : 6;
#pragma unroll
    for (int ky = 0; ky < 7; ++ky) {
      if (ky < ky_lo || ky > ky_hi) continue;  // compile-time folded
      const int orow = iy - ky;
#pragma unroll
      for (int kx = 0; kx < 7; ++kx) {
        const float zv = zr[ky * 7 + kx];
#pragma unroll
        for (int j = 0; j < 5; ++j)
          acc[orow][j] = fmaf(xr[kx + j], zv, acc[orow][j]);
      }
    }
  }

  // write the 5x5 tile (25 dword stores, imm offsets; L2 write-combines)
  float* ob = out + (size_t)plane * OPLANE + (ty * 5) * WO + tx * 5;
#pragma unroll
  for (int r = 0; r < 5; ++r)
#pragma unroll
    for (int j = 0; j < 5; ++j) ob[r * WO + j] = acc[r][j];
}

extern "C" void kernel_launch(void* const* d_in, const int* in_sizes, int n_in,
                              void* d_out, int out_size, void* d_ws, size_t ws_size,
                              hipStream_t stream) {
  const float* z = (const float*)d_in[0];  // [B,C,7,7]
  const float* x = (const float*)d_in[1];  // [B,C,31,31]
  float* out = (float*)d_out;              // [B,C,25,25]

  const int nplanes = in_sizes[0] / ZPLANE;  // 32768
  const int ntiles = nplanes * 25;           // 819200
  const int blocks = (ntiles + 255) / 256;   // 3200

  hipLaunchKernelGGL(dwxcorr_kernel, dim3(blocks), dim3(256), 0, stream,
                     z, x, out, ntiles);
}

// Round 5
// 50.729 us; speedup vs baseline: 1.4034x; 1.4034x over previous
//
#include <hip/hip_runtime.h>

// Depthwise xcorr: out[p][oy][ox] = sum_{ky,kx} x[p][oy+ky][ox+kx] * z[p][ky][kx]
// 32768 planes. x: 31x31, z: 7x7, out: 25x25, fp32.
//
// Round 5: LDS staging is back (round-4 direct-global was VMEM-latency-bound:
// VALU 14.6%, scattered 20B-stride lanes). Fixes vs round 3:
//  - LDS exactly 40960B (packed stride-31 planes + z) -> 4 blocks/CU (was 3)
//  - staging via async global_load_lds (linear layout, no div/mod, no
//    load->ds_write dependence chain)
//  - z staged too (49 LDS broadcast reads/thread instead of 49 VMEM loads)

#define PPB 10
#define WX 31
#define XPLANE 961            // 31*31 floats, packed (row stride 31)
#define ZPLANE 49
#define OPLANE 625
#define WO 25
#define XCHUNKS 38            // ceil(PPB*XPLANE/256) = ceil(9610/256)
#define XSLOTS (XCHUNKS * 256)  // 9728 floats = 38912 B
#define ZCHUNKS 2             // ceil(PPB*ZPLANE/256) = ceil(490/256)
#define ZSLOTS (ZCHUNKS * 256)  // 512 floats = 2048 B

typedef __attribute__((address_space(1))) const void gaddr_t;
typedef __attribute__((address_space(3))) void laddr_t;

__global__ __launch_bounds__(256) void dwxcorr_kernel(
    const float* __restrict__ z, const float* __restrict__ x,
    float* __restrict__ out, int nplanes) {
  __shared__ float xs[XSLOTS];  // 38912 B
  __shared__ float zs[ZSLOTS];  //  2048 B  -> total 40960 B, 4 blocks/CU

  const int tid = threadIdx.x;
  const int p0 = blockIdx.x * PPB;
  const int pmax = min(PPB, nplanes - p0);
  const long XTOT = (long)nplanes * XPLANE;
  const long ZTOT = (long)nplanes * ZPLANE;
  const long xoff = (long)p0 * XPLANE;
  const long zoff = (long)p0 * ZPLANE;
  const int wbase = tid & ~63;  // wave-uniform lane-0 slot of this wave's chunk

  // ---- async staging: x (38 chunks) + z (2 chunks), linear LDS layout ----
#pragma unroll
  for (int c = 0; c < XCHUNKS; ++c) {
    long gi = xoff + c * 256 + tid;
    if (gi >= XTOT) gi = XTOT - 1;  // tail-block clamp (dup data, never read)
    __builtin_amdgcn_global_load_lds((gaddr_t*)(x + gi),
                                     (laddr_t*)&xs[c * 256 + wbase], 4, 0, 0);
  }
#pragma unroll
  for (int c = 0; c < ZCHUNKS; ++c) {
    long gi = zoff + c * 256 + tid;
    if (gi >= ZTOT) gi = ZTOT - 1;
    __builtin_amdgcn_global_load_lds((gaddr_t*)(z + gi),
                                     (laddr_t*)&zs[c * 256 + wbase], 4, 0, 0);
  }
  __syncthreads();  // emits s_waitcnt vmcnt(0) lgkmcnt(0) + s_barrier

  // ---- compute: thread -> (plane pp, 5x5 output tile (ty,tx)) ----
  const int pp = tid / 25;
  if (pp >= pmax) return;  // threads 250..255 (and tail-block extras) done
  const int t25 = tid - pp * 25;
  const int ty = t25 / 5;
  const int tx = t25 - ty * 5;

  float zr[ZPLANE];
#pragma unroll
  for (int j = 0; j < ZPLANE; ++j) zr[j] = zs[pp * ZPLANE + j];

  float acc[5][5];
#pragma unroll
  for (int r = 0; r < 5; ++r)
#pragma unroll
    for (int j = 0; j < 5; ++j) acc[r][j] = 0.0f;

  const float* xbase = &xs[pp * XPLANE + (ty * 5) * WX + tx * 5];

  // Stream 11 patch rows; row iy feeds output rows orow = iy-ky in [0,4]
#pragma unroll
  for (int iy = 0; iy < 11; ++iy) {
    float xr[11];
#pragma unroll
    for (int k = 0; k < 11; ++k) xr[k] = xbase[iy * WX + k];
    const int ky_lo = (iy - 4 < 0) ? 0 : iy - 4;
    const int ky_hi = (iy < 6) ? iy : 6;
#pragma unroll
    for (int ky = 0; ky < 7; ++ky) {
      if (ky < ky_lo || ky > ky_hi) continue;  // compile-time folded
      const int orow = iy - ky;
#pragma unroll
      for (int kx = 0; kx < 7; ++kx) {
        const float zv = zr[ky * 7 + kx];
#pragma unroll
        for (int j = 0; j < 5; ++j)
          acc[orow][j] = fmaf(xr[kx + j], zv, acc[orow][j]);
      }
    }
  }

  // ---- write the 5x5 tile ----
  float* ob = out + (size_t)(p0 + pp) * OPLANE + (ty * 5) * WO + tx * 5;
#pragma unroll
  for (int r = 0; r < 5; ++r)
#pragma unroll
    for (int j = 0; j < 5; ++j) ob[r * WO + j] = acc[r][j];
}

extern "C" void kernel_launch(void* const* d_in, const int* in_sizes, int n_in,
                              void* d_out, int out_size, void* d_ws, size_t ws_size,
                              hipStream_t stream) {
  const float* z = (const float*)d_in[0];  // [B,C,7,7]
  const float* x = (const float*)d_in[1];  // [B,C,31,31]
  float* out = (float*)d_out;              // [B,C,25,25]

  const int nplanes = in_sizes[0] / ZPLANE;          // 32768
  const int blocks = (nplanes + PPB - 1) / PPB;      // 3277

  hipLaunchKernelGGL(dwxcorr_kernel, dim3(blocks), dim3(256), 0, stream,
                     z, x, out, nplanes);
}